// Round 4
// baseline (135.103 us; speedup 1.0000x reference)
//
#include <hip/hip_runtime.h>

// Problem constants (B=8, K=8192 from setup_inputs).
#define KPTS 8192
#define BATCH 8
#define TPB 256

#define ACC 8                        // adv points per thread
#define M_TILE (ACC * TPB)           // 2048
#define MT (KPTS / M_TILE)           // 4 m-tiles per batch
#define NT 64                        // n-slices per batch
#define N_SLICE (KPTS / NT)          // 128
#define GRID (BATCH * MT * NT)       // 2048 blocks

// Zero-initialized at module load. Encoding: slot = max over writers of
// ~bits(v), v nonneg  =>  decode min(v) = __uint_as_float(~slot).
// 0 is a strict bottom element (any stored value >= 0x80000000), so no init
// pass is needed and re-running with identical inputs is idempotent.
__device__ unsigned int g_ws[BATCH * KPTS];
__device__ unsigned int g_ticket;    // monotonic across graph replays

__global__ __launch_bounds__(TPB) void hausdorff_fused(
        const float* __restrict__ adv, const float* __restrict__ ori,
        const float* __restrict__ w, float* __restrict__ out) {
    __shared__ float4 sO[N_SLICE];   // (x, y, z, ||o||^2)

    const int bid = blockIdx.x;
    const int b  = bid >> 8;                 // / (MT*NT) = /256
    const int mt = (bid >> 6) & (MT - 1);
    const int nt = bid & (NT - 1);
    const int tid = threadIdx.x;

    // Stage this block's ori n-slice into LDS with precomputed ||o||^2.
    const float* op = ori + ((size_t)b * KPTS + (size_t)nt * N_SLICE) * 3;
    if (tid < N_SLICE) {
        float x = op[3 * tid + 0];
        float y = op[3 * tid + 1];
        float z = op[3 * tid + 2];
        sO[tid] = make_float4(x, y, z, x * x + y * y + z * z);
    }

    // Per-thread adv points: fold -2 into coords; ||a||^2 recomputed at end
    // (keeps the inner-loop register set at ~46 VGPRs, 8 waves/SIMD).
    float nax[ACC], nay[ACC], naz[ACC], mn[ACC];
    const float* ap = adv + ((size_t)b * KPTS + (size_t)mt * M_TILE) * 3;
#pragma unroll
    for (int i = 0; i < ACC; ++i) {
        int m = tid + i * TPB;
        nax[i] = -2.0f * ap[3 * m + 0];
        nay[i] = -2.0f * ap[3 * m + 1];
        naz[i] = -2.0f * ap[3 * m + 2];
        mn[i]  = __builtin_huge_valf();
    }
    __syncthreads();

    // 3.5 VALU/pair: 3 fma each for two n's, one v_min3 per pair of n's.
    // LDS traffic: 32 B per thread per 16 pairs = 2 B/pair (half of R3).
#pragma unroll 2
    for (int n = 0; n < N_SLICE; n += 2) {
        float4 o0 = sO[n];
        float4 o1 = sO[n + 1];
#pragma unroll
        for (int i = 0; i < ACC; ++i) {
            float t0 = fmaf(naz[i], o0.z, fmaf(nay[i], o0.y, fmaf(nax[i], o0.x, o0.w)));
            float t1 = fmaf(naz[i], o1.z, fmaf(nay[i], o1.y, fmaf(nax[i], o1.x, o1.w)));
            mn[i] = fminf(mn[i], fminf(t0, t1));   // -> v_min3_f32
        }
    }

    // Cross-slice combine via complement-encoded atomicMax (no init needed).
    unsigned int* wsb = g_ws + (size_t)b * KPTS + (size_t)mt * M_TILE;
#pragma unroll
    for (int i = 0; i < ACC; ++i) {
        int m = tid + i * TPB;
        float x = ap[3 * m + 0];
        float y = ap[3 * m + 1];
        float z = ap[3 * m + 2];
        float aa = fmaf(x, x, fmaf(y, y, z * z));
        float v = fmaxf(mn[i] + aa, 0.0f);
        atomicMax(wsb + m, ~__float_as_uint(v));
    }

    // ---- last-finisher block does the final reduction ----
    __shared__ unsigned int sLast;
    __syncthreads();                 // drains this block's vmcnt (atomics done)
    if (tid == 0) {
        __threadfence();             // release our atomics device-wide
        unsigned int t = atomicAdd(&g_ticket, 1u);
        // 2^32 % GRID == 0, so the modulo stays aligned across graph replays.
        sLast = ((t % GRID) == (GRID - 1)) ? 1u : 0u;
    }
    __syncthreads();
    if (!sLast) return;

    float mx[BATCH];
#pragma unroll
    for (int j = 0; j < BATCH; ++j) mx[j] = -1.0f;
    for (int m = tid; m < KPTS; m += TPB) {
#pragma unroll
        for (int j = 0; j < BATCH; ++j) {
            unsigned int u = __hip_atomic_load(&g_ws[(size_t)j * KPTS + m],
                                               __ATOMIC_RELAXED,
                                               __HIP_MEMORY_SCOPE_AGENT);
            mx[j] = fmaxf(mx[j], __uint_as_float(~u));   // decode min_n dist
        }
    }
#pragma unroll
    for (int j = 0; j < BATCH; ++j)
#pragma unroll
        for (int off = 32; off; off >>= 1)
            mx[j] = fmaxf(mx[j], __shfl_down(mx[j], off, 64));

    __shared__ float red[TPB / 64][BATCH];
    if ((tid & 63) == 0)
#pragma unroll
        for (int j = 0; j < BATCH; ++j) red[tid >> 6][j] = mx[j];
    __syncthreads();
    if (tid == 0) {
        float s = 0.0f;
#pragma unroll
        for (int j = 0; j < BATCH; ++j) {
            float v = red[0][j];
#pragma unroll
            for (int r = 1; r < TPB / 64; ++r) v = fmaxf(v, red[r][j]);
            s += v * w[j];
        }
        out[0] = s * (1.0f / BATCH);   // single writer — no zeroing needed
    }
}

extern "C" void kernel_launch(void* const* d_in, const int* in_sizes, int n_in,
                              void* d_out, int out_size, void* d_ws, size_t ws_size,
                              hipStream_t stream) {
    const float* adv = (const float*)d_in[0];   // [B, K, 3]
    const float* ori = (const float*)d_in[1];   // [B, K, 3]
    const float* w   = (const float*)d_in[2];   // [B]
    float* out = (float*)d_out;
    (void)d_ws; (void)ws_size;

    hausdorff_fused<<<GRID, TPB, 0, stream>>>(adv, ori, w, out);
}

// Round 6
// 107.812 us; speedup vs baseline: 1.2531x; 1.2531x over previous
//
#include <hip/hip_runtime.h>

// Problem constants (B=8, K=8192 from setup_inputs).
#define KPTS 8192
#define BATCH 8
#define TPB 256

#define ACC 8                        // adv points per thread
#define M_TILE (ACC * TPB)           // 2048
#define MT (KPTS / M_TILE)           // 4 m-tiles per batch
#define NT 64                        // n-slices per batch
#define N_SLICE (KPTS / NT)          // 128
#define GRID_A (BATCH * MT * NT)     // 2048 blocks = 8/CU = 32 waves/CU

#define SB 32                        // phaseB blocks per batch
#define GRID_B (BATCH * SB)          // 256 blocks; each owns TPB m-points

// Scratch in device globals (not d_ws): every element is overwritten before
// it is read on every call, so no init pass, no atomics, replay-idempotent.
__device__ float g_ws[(size_t)BATCH * NT * KPTS];   // 16.8 MB partial mins
__device__ float g_partial[GRID_B];                 // per-block maxes

// ---- phaseA: per (b, m-tile, n-slice) partial min, plain stores ----------
__global__ __launch_bounds__(TPB) void phaseA(const float* __restrict__ adv,
                                              const float* __restrict__ ori) {
    __shared__ float4 sO[N_SLICE];   // (x, y, z, ||o||^2)

    const int bid = blockIdx.x;
    const int b  = bid >> 8;                 // / (MT*NT) = /256
    const int mt = (bid >> 6) & (MT - 1);
    const int nt = bid & (NT - 1);
    const int tid = threadIdx.x;

    const float* op = ori + ((size_t)b * KPTS + (size_t)nt * N_SLICE) * 3;
    if (tid < N_SLICE) {
        float x = op[3 * tid + 0];
        float y = op[3 * tid + 1];
        float z = op[3 * tid + 2];
        sO[tid] = make_float4(x, y, z, x * x + y * y + z * z);
    }

    // Fold -2 into adv coords; ||a||^2 recomputed in the epilogue (L2-hit
    // refetch) to keep the inner-loop register set small.
    float nax[ACC], nay[ACC], naz[ACC], mn[ACC];
    const float* ap = adv + ((size_t)b * KPTS + (size_t)mt * M_TILE) * 3;
#pragma unroll
    for (int i = 0; i < ACC; ++i) {
        int m = tid + i * TPB;               // tile-local adv index
        nax[i] = -2.0f * ap[3 * m + 0];
        nay[i] = -2.0f * ap[3 * m + 1];
        naz[i] = -2.0f * ap[3 * m + 2];
        mn[i]  = __builtin_huge_valf();
    }
    __syncthreads();

    // 3.5 VALU/pair: 3 fma per point, one v_min3 per two n's.
    // LDS: 32 B / thread / 16 pairs = 2 B/pair (below VALU demand).
#pragma unroll 2
    for (int n = 0; n < N_SLICE; n += 2) {
        float4 o0 = sO[n];
        float4 o1 = sO[n + 1];
#pragma unroll
        for (int i = 0; i < ACC; ++i) {
            float t0 = fmaf(naz[i], o0.z, fmaf(nay[i], o0.y, fmaf(nax[i], o0.x, o0.w)));
            float t1 = fmaf(naz[i], o1.z, fmaf(nay[i], o1.y, fmaf(nax[i], o1.x, o1.w)));
            mn[i] = fminf(mn[i], fminf(t0, t1));   // -> v_min3_f32
        }
    }

    // Plain coalesced stores — no RMW, no contention, no init required.
    // wsb already includes the mt*M_TILE offset; m is tile-local, so the
    // slice-global index is wsb[m].  (R5 bug: subtracted mt*M_TILE again.)
    float* wsb = g_ws + ((size_t)(b * NT + nt)) * KPTS + (size_t)mt * M_TILE;
#pragma unroll
    for (int i = 0; i < ACC; ++i) {
        int m = tid + i * TPB;               // tile-local
        float x = ap[3 * m + 0];
        float y = ap[3 * m + 1];
        float z = ap[3 * m + 2];
        float aa = fmaf(x, x, fmaf(y, y, z * z));
        wsb[m] = mn[i] + aa;
    }
}

// ---- phaseB: min over NT slices, block max-reduce, one partial per block --
__global__ __launch_bounds__(TPB) void phaseB() {
    const int blk = blockIdx.x;              // GRID_B = B * SB
    const int b   = blk / SB;
    const int sb  = blk % SB;
    const int tid = threadIdx.x;
    const int m   = sb * TPB + tid;          // this thread's adv point

    const float* base = g_ws + ((size_t)b * NT) * KPTS + m;
    float m0 = __builtin_huge_valf(), m1 = m0, m2 = m0, m3 = m0;
#pragma unroll
    for (int t = 0; t < NT; t += 4) {        // 4 independent min chains (MLP)
        m0 = fminf(m0, base[(size_t)(t + 0) * KPTS]);
        m1 = fminf(m1, base[(size_t)(t + 1) * KPTS]);
        m2 = fminf(m2, base[(size_t)(t + 2) * KPTS]);
        m3 = fminf(m3, base[(size_t)(t + 3) * KPTS]);
    }
    float v = fminf(fminf(m0, m1), fminf(m2, m3));   // min_n dist^2 for m

#pragma unroll
    for (int off = 32; off; off >>= 1)
        v = fmaxf(v, __shfl_down(v, off, 64));

    __shared__ float red[TPB / 64];
    if ((tid & 63) == 0) red[tid >> 6] = v;
    __syncthreads();
    if (tid == 0)
        g_partial[blk] = fmaxf(fmaxf(red[0], red[1]), fmaxf(red[2], red[3]));
}

// ---- phaseC: single wave -> weighted mean, single writer ------------------
__global__ void phaseC(const float* __restrict__ w, float* __restrict__ out) {
    const int tid = threadIdx.x;             // 64 threads
    float v = 0.0f;
    if (tid < BATCH) {
        float mx = -__builtin_huge_valf();
#pragma unroll
        for (int i = 0; i < SB; ++i)
            mx = fmaxf(mx, g_partial[tid * SB + i]);
        v = mx * w[tid] * (1.0f / BATCH);
    }
#pragma unroll
    for (int off = 4; off; off >>= 1)        // sum lanes 0..7
        v += __shfl_down(v, off, 64);
    if (tid == 0) out[0] = v;
}

extern "C" void kernel_launch(void* const* d_in, const int* in_sizes, int n_in,
                              void* d_out, int out_size, void* d_ws, size_t ws_size,
                              hipStream_t stream) {
    const float* adv = (const float*)d_in[0];   // [B, K, 3]
    const float* ori = (const float*)d_in[1];   // [B, K, 3]
    const float* w   = (const float*)d_in[2];   // [B]
    float* out = (float*)d_out;
    (void)d_ws; (void)ws_size;

    phaseA<<<GRID_A, TPB, 0, stream>>>(adv, ori);
    phaseB<<<GRID_B, TPB, 0, stream>>>();
    phaseC<<<1, 64, 0, stream>>>(w, out);
}